// Round 5
// baseline (604.910 us; speedup 1.0000x reference)
//
#include <hip/hip_runtime.h>
#include <math.h>

#define CEXP 2.8853900817779268f  // 2*log2(e): tanh(z) = 1 - 2/(2^(c*z)+1)
#define TABN 2048   // s(theta) table cells
#define NC   320    // w(x) grid cells per axis
#define NN   321    // w(x) grid nodes per axis
#define NNODES (NN * NN)                     // 103041
#define WGB2 ((NNODES + 127) / 128)          // 806 one-wave blocks, 2 nodes/thread
#define SGB (TABN / 64)                      // 32 one-wave blocks for the s-table

// Tables (rewritten by prep_kernel on every launch; kernel boundary makes
// them visible to interior_kernel across XCDs).
// g_ctab[node] = {w0+y*w4, w1+y*w5, w2+y*w6, w3+y*w7} with y = yita(|node-imv|)
// folded at prep time -> 16 B/node. 1.65 MB, L2-resident.
__device__ float4 g_ctab[NNODES];
__device__ float2 g_stab2[TABN];        // cell i: {s(p_i), s(p_{i+1}) - s(p_i)}

// tanh with the 2*log2(e) factor pre-folded into the incoming accumulator.
static __device__ __forceinline__ float tanh_pre(float z) {
    float e = __builtin_amdgcn_exp2f(z);
    float r = __builtin_amdgcn_rcpf(e + 1.0f);
    return fmaf(-2.0f, r, 1.0f);
}

// Full phi-branch value s(theta(p)) at diamond-angle parameter p in [-2,2].
// ROUND-2 LESSON: keep this UN-unrolled with libm tanhf (the unrolled
// tanh_pre version spilled to scratch and became a long serial tail).
static __device__ float s_of_p(float pth,
    const float* __restrict__ Wp1, const float* __restrict__ bp1,
    const float* __restrict__ Wp2, const float* __restrict__ bp2,
    const float* __restrict__ Wp3, const float* __restrict__ bp3,
    const float* __restrict__ Wp4, const float* __restrict__ bp4)
{
    float th;
    if (pth >= -1.0f && pth <= 1.0f) {
        th = atanf(pth / (1.0f - fabsf(pth)));      // /0 -> inf -> atan=pi/2 ok
    } else if (pth > 1.0f) {
        const float uu = 2.0f - pth;                // [0,1)
        th = (float)M_PI - atanf(uu / (1.0f - uu));
    } else {
        const float uu = -2.0f - pth;               // (-1,0]
        th = -(float)M_PI + atanf(-uu / (1.0f + uu));
    }
    const float cth = cosf(th), sth = sinf(th);

    // phi-MLP in f32 with exact tanh: 2 -> 15 -> 15 -> 15 -> 4
    float h[15], h2[15];
    for (int j = 0; j < 15; ++j)
        h[j] = tanhf(cth * Wp1[j] + sth * Wp1[15 + j] + bp1[j]);
    for (int j = 0; j < 15; ++j) {
        float a = bp2[j];
        for (int k = 0; k < 15; ++k) a += h[k] * Wp2[k * 15 + j];
        h2[j] = tanhf(a);
    }
    for (int j = 0; j < 15; ++j) {
        float a = bp3[j];
        for (int k = 0; k < 15; ++k) a += h2[k] * Wp3[k * 15 + j];
        h[j] = tanhf(a);
    }
    float ph[4];
    for (int j = 0; j < 4; ++j) {
        float a = bp4[j];
        for (int k = 0; k < 15; ++k) a += h[k] * Wp4[k * 4 + j];
        ph[j] = a;
    }
    return ph[0] + ph[1] * sinf(0.5f * th) + ph[2] * sth + ph[3] * sinf(1.5f * th);
}

// ROUND-5 STRUCTURE: LDS-staged weights (the only staging that ever worked:
// round-0 = 31.6us; scalar s_load = 73us serial-latency, LDS-b128-split = 40us)
// but with the LDS-pipe demand halved PER NODE: 64-thread one-wave blocks,
// TWO nodes per thread. The weight scan (~1860 floats, broadcast ds_reads) is
// per-THREAD, so 2 nodes/thread halves LDS instructions per node; inner loop
// is 4x ds_read_b128 (48cy) feeding 32 FMAs (64cy) per k-half -> VALU-leaning.
// 806 blocks = 3.1 waves/CU (balanced tail vs 403 fat blocks' 27%).
// j-half blocking (16-wide acc) keeps live VGPRs ~140: h(60)+acc(32)+w(16).
__global__ __launch_bounds__(64, 2) void prep_kernel(
    const float* __restrict__ imv,
    const float* __restrict__ Ww1, const float* __restrict__ bw1,
    const float* __restrict__ Ww2, const float* __restrict__ bw2,
    const float* __restrict__ Ww3, const float* __restrict__ bw3,
    const float* __restrict__ Ww4, const float* __restrict__ bw4,
    const float* __restrict__ Wp1, const float* __restrict__ bp1,
    const float* __restrict__ Wp2, const float* __restrict__ bp2,
    const float* __restrict__ Wp3, const float* __restrict__ bp3,
    const float* __restrict__ Wp4, const float* __restrict__ bp4)
{
    const int t = threadIdx.x;

    if (blockIdx.x < WGB2) {
        // ---- stage prescaled weights into LDS, [k][32] padded layout ----
        __shared__ __align__(16) float sW1[64], sb1[32];
        __shared__ __align__(16) float sW2[30 * 32], sb2[32];
        __shared__ __align__(16) float sW3[30 * 32], sb3[32];
        __shared__ __align__(16) float sW4[30 * 8],  sb4[8];
        for (int i = t; i < 960; i += 64) {
            const int k = i >> 5, c = i & 31;
            const bool pad = (c >= 30);
            sW2[i] = pad ? 0.0f : CEXP * Ww2[k * 30 + c];
            sW3[i] = pad ? 0.0f : CEXP * Ww3[k * 30 + c];
        }
        for (int i = t; i < 240; i += 64) sW4[i] = Ww4[i];
        if (t < 60) sW1[t] = CEXP * Ww1[t];
        if (t < 32) {
            sb2[t] = (t < 30) ? CEXP * bw2[t] : 0.0f;
            sb3[t] = (t < 30) ? CEXP * bw3[t] : 0.0f;
        }
        if (t < 30) sb1[t] = CEXP * bw1[t];
        if (t < 8)  sb4[t] = bw4[t];
        __syncthreads();

        const int base = blockIdx.x * 128 + t;
        const int g0 = base < NNODES ? base : NNODES - 1;          // clamp
        const int g1 = base + 64 < NNODES ? base + 64 : NNODES - 1;
        const int ix0 = g0 % NN, iy0 = g0 / NN;
        const int ix1 = g1 % NN, iy1 = g1 / NN;
        const float p00 = (float)ix0 * (1.0f / (float)NC);
        const float p01 = (float)iy0 * (1.0f / (float)NC);
        const float p10 = (float)ix1 * (1.0f / (float)NC);
        const float p11 = (float)iy1 * (1.0f / (float)NC);
        const float im0 = imv[0], im1 = imv[1];

        // ---- layer 1: 2 -> 30, both nodes (weights read once) ----
        float h0[30], h1[30];
        #pragma unroll
        for (int j = 0; j < 30; ++j) {
            const float wa = sW1[j], wb = sW1[30 + j], bb = sb1[j];
            h0[j] = tanh_pre(fmaf(p01, wb, fmaf(p00, wa, bb)));
            h1[j] = tanh_pre(fmaf(p11, wb, fmaf(p10, wa, bb)));
        }

        // ---- layer 2: 30 -> 30, j-half blocked ----
        float a0[30], a1[30];
        #pragma unroll
        for (int half = 0; half < 2; ++half) {
            float c0[16], c1[16];
            #pragma unroll
            for (int m = 0; m < 16; ++m) { c0[m] = sb2[half * 16 + m]; c1[m] = c0[m]; }
            #pragma unroll
            for (int k = 0; k < 30; ++k) {
                const float* Wr = &sW2[k * 32 + half * 16];
                const float4 wA = *(const float4*)&Wr[0];
                const float4 wB = *(const float4*)&Wr[4];
                const float4 wC = *(const float4*)&Wr[8];
                const float4 wD = *(const float4*)&Wr[12];
                const float q0 = h0[k], q1 = h1[k];
                c0[0]  = fmaf(q0, wA.x, c0[0]);  c1[0]  = fmaf(q1, wA.x, c1[0]);
                c0[1]  = fmaf(q0, wA.y, c0[1]);  c1[1]  = fmaf(q1, wA.y, c1[1]);
                c0[2]  = fmaf(q0, wA.z, c0[2]);  c1[2]  = fmaf(q1, wA.z, c1[2]);
                c0[3]  = fmaf(q0, wA.w, c0[3]);  c1[3]  = fmaf(q1, wA.w, c1[3]);
                c0[4]  = fmaf(q0, wB.x, c0[4]);  c1[4]  = fmaf(q1, wB.x, c1[4]);
                c0[5]  = fmaf(q0, wB.y, c0[5]);  c1[5]  = fmaf(q1, wB.y, c1[5]);
                c0[6]  = fmaf(q0, wB.z, c0[6]);  c1[6]  = fmaf(q1, wB.z, c1[6]);
                c0[7]  = fmaf(q0, wB.w, c0[7]);  c1[7]  = fmaf(q1, wB.w, c1[7]);
                c0[8]  = fmaf(q0, wC.x, c0[8]);  c1[8]  = fmaf(q1, wC.x, c1[8]);
                c0[9]  = fmaf(q0, wC.y, c0[9]);  c1[9]  = fmaf(q1, wC.y, c1[9]);
                c0[10] = fmaf(q0, wC.z, c0[10]); c1[10] = fmaf(q1, wC.z, c1[10]);
                c0[11] = fmaf(q0, wC.w, c0[11]); c1[11] = fmaf(q1, wC.w, c1[11]);
                c0[12] = fmaf(q0, wD.x, c0[12]); c1[12] = fmaf(q1, wD.x, c1[12]);
                c0[13] = fmaf(q0, wD.y, c0[13]); c1[13] = fmaf(q1, wD.y, c1[13]);
                c0[14] = fmaf(q0, wD.z, c0[14]); c1[14] = fmaf(q1, wD.z, c1[14]);
                c0[15] = fmaf(q0, wD.w, c0[15]); c1[15] = fmaf(q1, wD.w, c1[15]);
            }
            #pragma unroll
            for (int m = 0; m < 16; ++m) {
                const int j = half * 16 + m;
                if (j < 30) { a0[j] = tanh_pre(c0[m]); a1[j] = tanh_pre(c1[m]); }
            }
        }

        // ---- layer 3: 30 -> 30 ----
        float b0[30], b1[30];
        #pragma unroll
        for (int half = 0; half < 2; ++half) {
            float c0[16], c1[16];
            #pragma unroll
            for (int m = 0; m < 16; ++m) { c0[m] = sb3[half * 16 + m]; c1[m] = c0[m]; }
            #pragma unroll
            for (int k = 0; k < 30; ++k) {
                const float* Wr = &sW3[k * 32 + half * 16];
                const float4 wA = *(const float4*)&Wr[0];
                const float4 wB = *(const float4*)&Wr[4];
                const float4 wC = *(const float4*)&Wr[8];
                const float4 wD = *(const float4*)&Wr[12];
                const float q0 = a0[k], q1 = a1[k];
                c0[0]  = fmaf(q0, wA.x, c0[0]);  c1[0]  = fmaf(q1, wA.x, c1[0]);
                c0[1]  = fmaf(q0, wA.y, c0[1]);  c1[1]  = fmaf(q1, wA.y, c1[1]);
                c0[2]  = fmaf(q0, wA.z, c0[2]);  c1[2]  = fmaf(q1, wA.z, c1[2]);
                c0[3]  = fmaf(q0, wA.w, c0[3]);  c1[3]  = fmaf(q1, wA.w, c1[3]);
                c0[4]  = fmaf(q0, wB.x, c0[4]);  c1[4]  = fmaf(q1, wB.x, c1[4]);
                c0[5]  = fmaf(q0, wB.y, c0[5]);  c1[5]  = fmaf(q1, wB.y, c1[5]);
                c0[6]  = fmaf(q0, wB.z, c0[6]);  c1[6]  = fmaf(q1, wB.z, c1[6]);
                c0[7]  = fmaf(q0, wB.w, c0[7]);  c1[7]  = fmaf(q1, wB.w, c1[7]);
                c0[8]  = fmaf(q0, wC.x, c0[8]);  c1[8]  = fmaf(q1, wC.x, c1[8]);
                c0[9]  = fmaf(q0, wC.y, c0[9]);  c1[9]  = fmaf(q1, wC.y, c1[9]);
                c0[10] = fmaf(q0, wC.z, c0[10]); c1[10] = fmaf(q1, wC.z, c1[10]);
                c0[11] = fmaf(q0, wC.w, c0[11]); c1[11] = fmaf(q1, wC.w, c1[11]);
                c0[12] = fmaf(q0, wD.x, c0[12]); c1[12] = fmaf(q1, wD.x, c1[12]);
                c0[13] = fmaf(q0, wD.y, c0[13]); c1[13] = fmaf(q1, wD.y, c1[13]);
                c0[14] = fmaf(q0, wD.z, c0[14]); c1[14] = fmaf(q1, wD.z, c1[14]);
                c0[15] = fmaf(q0, wD.w, c0[15]); c1[15] = fmaf(q1, wD.w, c1[15]);
            }
            #pragma unroll
            for (int m = 0; m < 16; ++m) {
                const int j = half * 16 + m;
                if (j < 30) { b0[j] = tanh_pre(c0[m]); b1[j] = tanh_pre(c1[m]); }
            }
        }

        // ---- layer 4: 30 -> 8 ----
        float o0[8], o1[8];
        #pragma unroll
        for (int j = 0; j < 8; ++j) { o0[j] = sb4[j]; o1[j] = sb4[j]; }
        #pragma unroll
        for (int k = 0; k < 30; ++k) {
            const float4 wA = *(const float4*)&sW4[k * 8];
            const float4 wB = *(const float4*)&sW4[k * 8 + 4];
            const float q0 = b0[k], q1 = b1[k];
            o0[0] = fmaf(q0, wA.x, o0[0]); o1[0] = fmaf(q1, wA.x, o1[0]);
            o0[1] = fmaf(q0, wA.y, o0[1]); o1[1] = fmaf(q1, wA.y, o1[1]);
            o0[2] = fmaf(q0, wA.z, o0[2]); o1[2] = fmaf(q1, wA.z, o1[2]);
            o0[3] = fmaf(q0, wA.w, o0[3]); o1[3] = fmaf(q1, wA.w, o1[3]);
            o0[4] = fmaf(q0, wB.x, o0[4]); o1[4] = fmaf(q1, wB.x, o1[4]);
            o0[5] = fmaf(q0, wB.y, o0[5]); o1[5] = fmaf(q1, wB.y, o1[5]);
            o0[6] = fmaf(q0, wB.z, o0[6]); o1[6] = fmaf(q1, wB.z, o1[6]);
            o0[7] = fmaf(q0, wB.w, o0[7]); o1[7] = fmaf(q1, wB.w, o1[7]);
        }

        // ---- fold yita(node): c_j = w_j + y * w_{4+j}  (16 B/node) ----
        {
            const float ddx = p00 - im0, ddy = p01 - im1;
            const float rr  = sqrtf(fmaf(ddx, ddx, ddy * ddy));
            const float tt  = fminf(fmaxf(fmaf(2.5f, rr, -1.25f), 0.0f), 1.0f);
            const float tt3 = tt * tt * tt;
            const float yv  = fmaf(fmaf(fmaf(-6.0f, tt, 15.0f), tt, -10.0f), tt3, 1.0f);
            float4 v;
            v.x = fmaf(yv, o0[4], o0[0]);
            v.y = fmaf(yv, o0[5], o0[1]);
            v.z = fmaf(yv, o0[6], o0[2]);
            v.w = fmaf(yv, o0[7], o0[3]);
            if (base < NNODES) g_ctab[g0] = v;
        }
        {
            const float ddx = p10 - im0, ddy = p11 - im1;
            const float rr  = sqrtf(fmaf(ddx, ddx, ddy * ddy));
            const float tt  = fminf(fmaxf(fmaf(2.5f, rr, -1.25f), 0.0f), 1.0f);
            const float tt3 = tt * tt * tt;
            const float yv  = fmaf(fmaf(fmaf(-6.0f, tt, 15.0f), tt, -10.0f), tt3, 1.0f);
            float4 v;
            v.x = fmaf(yv, o1[4], o1[0]);
            v.y = fmaf(yv, o1[5], o1[1]);
            v.z = fmaf(yv, o1[6], o1[2]);
            v.w = fmaf(yv, o1[7], o1[3]);
            if (base + 64 < NNODES) g_ctab[g1] = v;
        }
        return;
    }

    // ---- s(theta) table blocks ----
    const int cell = (blockIdx.x - WGB2) * 64 + t;
    if (cell < TABN) {
        const float hh = 4.0f / (float)TABN;
        const float p0 = -2.0f + hh * (float)cell;
        const float s0 = s_of_p(p0,      Wp1, bp1, Wp2, bp2, Wp3, bp3, Wp4, bp4);
        const float s1 = s_of_p(p0 + hh, Wp1, bp1, Wp2, bp2, Wp3, bp3, Wp4, bp4);
        float2 e; e.x = s0; e.y = s1 - s0;
        g_stab2[cell] = e;
    }
}

// 2 points per thread. Per point: one bilinear gather of the 4 folded coeffs
// (4x dwordx4), one 8 B s(theta) gather, ~70 VALU ops of closed-form geometry.
__global__ __launch_bounds__(256) void interior_kernel(
    const float4* __restrict__ x,      // two points per float4
    const float*  __restrict__ imv,
    const float*  __restrict__ lmbd,
    float* __restrict__ out, int n2)   // n2 = n/2
{
    const int idx = blockIdx.x * blockDim.x + threadIdx.x;
    if (idx >= n2) return;

    const float4 xx = x[idx];
    const float X0[2] = {xx.x, xx.z};
    const float X1[2] = {xx.y, xx.w};
    const float im0 = imv[0], im1 = imv[1], lam = lmbd[0];

    const float4* __restrict__ T = g_ctab;

    float res[2];
    #pragma unroll
    for (int p = 0; p < 2; ++p) {
        const float x0 = X0[p], x1 = X1[p];

        // ---- bilinear gather of folded coeffs c[0..4) from the 2-D grid ----
        const float fx = x0 * (float)NC;
        const float fy = x1 * (float)NC;
        int ix = (int)fx; ix = ix < 0 ? 0 : (ix > NC - 1 ? NC - 1 : ix);
        int iy = (int)fy; iy = iy < 0 ? 0 : (iy > NC - 1 ? NC - 1 : iy);
        const float frx = fx - (float)ix;
        const float fry = fy - (float)iy;

        const int k = iy * NN + ix;              // float4 units
        const float4 A = T[k],      B = T[k + 1];        // (ix,iy) (ix+1,iy)
        const float4 Cq = T[k + NN], D = T[k + NN + 1];  // row iy+1

        float cv[4];
        {
            const float r0x = fmaf(frx, B.x - A.x, A.x);
            const float r0y = fmaf(frx, B.y - A.y, A.y);
            const float r0z = fmaf(frx, B.z - A.z, A.z);
            const float r0w = fmaf(frx, B.w - A.w, A.w);
            const float r1x = fmaf(frx, D.x - Cq.x, Cq.x);
            const float r1y = fmaf(frx, D.y - Cq.y, Cq.y);
            const float r1z = fmaf(frx, D.z - Cq.z, Cq.z);
            const float r1w = fmaf(frx, D.w - Cq.w, Cq.w);
            cv[0] = fmaf(fry, r1x - r0x, r0x);
            cv[1] = fmaf(fry, r1y - r0y, r0y);
            cv[2] = fmaf(fry, r1z - r0z, r0z);
            cv[3] = fmaf(fry, r1w - r0w, r0w);
        }

        // ---- geometry about the interior vertex ----
        const float dx = x0 - im0, dy = x1 - im1;
        const float r  = sqrtf(fmaf(dx, dx, dy * dy));

        // yita(r) -- exact, still needed for the sp term
        const float t  = fminf(fmaxf(fmaf(2.5f, r, -1.25f), 0.0f), 1.0f);
        const float t3 = t * t * t;
        const float yv = fmaf(fmaf(fmaf(-6.0f, t, 15.0f), t, -10.0f), t3, 1.0f);

        // r^lambda (sqrt fast path for lambda == 0.5)
        float rl;
        if (lam == 0.5f) rl = sqrtf(r);
        else rl = __builtin_amdgcn_exp2f(lam * __builtin_amdgcn_logf(fmaxf(r, 1e-20f)));

        // diamond-angle parameter p(theta) in [-2,2], no trig
        const float l1n = fmaxf(fabsf(dx) + fabsf(dy), 1e-20f);
        const float u   = dy * __builtin_amdgcn_rcpf(l1n);
        const float pbk = (dy >= 0.0f) ? (2.0f - u) : (-2.0f - u);
        const float pth = (dx >= 0.0f) ? u : pbk;

        // s(theta) table gather: cell {s, ds}, one 8 B load
        const float fi = fminf(fmaxf(fmaf(pth, (float)(TABN / 4), (float)(TABN / 2)),
                                     0.0f), (float)TABN - 0.001f);
        const int   ii = (int)fi;
        const float fr = fi - (float)ii;
        const float2 sd = g_stab2[ii];
        const float sval = fmaf(fr, sd.y, sd.x);

        // singular functions at x (about origin), algebraically reduced:
        // vp0 = r0^0.5 sin(th/2) = copysign(sqrt((r0-x0)/2), x1)
        // vp1 = x1
        // vp2 = r0^1.5 sin(1.5 th) = x1*sqrt((r0+x0)/2) + x0*vp0
        const float r0 = sqrtf(fmaf(x0, x0, x1 * x1));
        const float Aq = sqrtf(fmaxf(0.0f, (r0 - x0) * 0.5f));
        const float Bq = sqrtf(fmaxf(0.0f, (r0 + x0) * 0.5f));
        const float vp0 = copysignf(Aq, x1);
        const float vp2 = fmaf(x1, Bq, x0 * vp0);

        // combine (yita already folded into cv[])
        float rp = cv[0];
        rp = fmaf(cv[1], vp0, rp);
        rp = fmaf(cv[2], x1, rp);
        rp = fmaf(cv[3], vp2, rp);
        res[p] = fmaf(sval * yv, rl, rp);
    }

    float2 o; o.x = res[0]; o.y = res[1];
    ((float2*)out)[idx] = o;
}

extern "C" void kernel_launch(void* const* d_in, const int* in_sizes, int n_in,
                              void* d_out, int out_size, void* d_ws, size_t ws_size,
                              hipStream_t stream) {
    const float4* x   = (const float4*)d_in[0];
    const float* imv  = (const float*)d_in[1];
    const float* lmbd = (const float*)d_in[2];
    const float* Ww1  = (const float*)d_in[3];
    const float* bw1  = (const float*)d_in[4];
    const float* Ww2  = (const float*)d_in[5];
    const float* bw2  = (const float*)d_in[6];
    const float* Ww3  = (const float*)d_in[7];
    const float* bw3  = (const float*)d_in[8];
    const float* Ww4  = (const float*)d_in[9];
    const float* bw4  = (const float*)d_in[10];
    const float* Wp1  = (const float*)d_in[11];
    const float* bp1  = (const float*)d_in[12];
    const float* Wp2  = (const float*)d_in[13];
    const float* bp2  = (const float*)d_in[14];
    const float* Wp3  = (const float*)d_in[15];
    const float* bp3  = (const float*)d_in[16];
    const float* Wp4  = (const float*)d_in[17];
    const float* bp4  = (const float*)d_in[18];
    float* out = (float*)d_out;

    const int n  = in_sizes[0] / 2;
    const int n2 = n / 2;

    // WGB2 one-wave blocks for the w-grid (2 nodes/thread) + SGB s-table blocks.
    prep_kernel<<<WGB2 + SGB, 64, 0, stream>>>(
        imv,
        Ww1, bw1, Ww2, bw2, Ww3, bw3, Ww4, bw4,
        Wp1, bp1, Wp2, bp2, Wp3, bp3, Wp4, bp4);

    const int block = 256;
    const int grid = (n2 + block - 1) / block;
    interior_kernel<<<grid, block, 0, stream>>>(x, imv, lmbd, out, n2);
}

// Round 7
// 137.400 us; speedup vs baseline: 4.4026x; 4.4026x over previous
//
#include <hip/hip_runtime.h>
#include <math.h>

#define CEXP 2.8853900817779268f  // 2*log2(e): tanh(z) = 1 - 2/(2^(c*z)+1)
#define TABN 2048   // s(theta) table cells
#define NC   320    // w(x) grid cells per axis
#define NN   321    // w(x) grid nodes per axis
#define NNODES (NN * NN)                 // 103041
#define WGB ((NNODES + 63) / 64)         // 1611 one-wave blocks for the w-grid
#define SGB (TABN / 64)                  // 32 one-wave blocks for the s-table

// Tables (rewritten by prep_kernel on every launch; kernel boundary makes
// them visible to interior_kernel across XCDs).
// g_ctab[node] = {w0+y*w4, w1+y*w5, w2+y*w6, w3+y*w7} with y = yita(|node-imv|)
// folded at prep time -> 16 B/node. 1.65 MB, L2-resident. (Fold verified
// passing in rounds 3 and 5.)
__device__ float4 g_ctab[NNODES];
__device__ float2 g_stab2[TABN];        // cell i: {s(p_i), s(p_{i+1}) - s(p_i)}

// tanh with the 2*log2(e) factor pre-folded into the incoming accumulator.
static __device__ __forceinline__ float tanh_pre(float z) {
    float e = __builtin_amdgcn_exp2f(z);
    float r = __builtin_amdgcn_rcpf(e + 1.0f);
    return fmaf(-2.0f, r, 1.0f);
}

// Full phi-branch value s(theta(p)) at diamond-angle parameter p in [-2,2].
// ROUND-2 LESSON: keep this UN-unrolled with libm tanhf (the unrolled
// tanh_pre version spilled to scratch and became a long serial tail).
static __device__ float s_of_p(float pth,
    const float* __restrict__ Wp1, const float* __restrict__ bp1,
    const float* __restrict__ Wp2, const float* __restrict__ bp2,
    const float* __restrict__ Wp3, const float* __restrict__ bp3,
    const float* __restrict__ Wp4, const float* __restrict__ bp4)
{
    float th;
    if (pth >= -1.0f && pth <= 1.0f) {
        th = atanf(pth / (1.0f - fabsf(pth)));      // /0 -> inf -> atan=pi/2 ok
    } else if (pth > 1.0f) {
        const float uu = 2.0f - pth;                // [0,1)
        th = (float)M_PI - atanf(uu / (1.0f - uu));
    } else {
        const float uu = -2.0f - pth;               // (-1,0]
        th = -(float)M_PI + atanf(-uu / (1.0f + uu));
    }
    const float cth = cosf(th), sth = sinf(th);

    // phi-MLP in f32 with exact tanh: 2 -> 15 -> 15 -> 15 -> 4
    float h[15], h2[15];
    for (int j = 0; j < 15; ++j)
        h[j] = tanhf(cth * Wp1[j] + sth * Wp1[15 + j] + bp1[j]);
    for (int j = 0; j < 15; ++j) {
        float a = bp2[j];
        for (int k = 0; k < 15; ++k) a += h[k] * Wp2[k * 15 + j];
        h2[j] = tanhf(a);
    }
    for (int j = 0; j < 15; ++j) {
        float a = bp3[j];
        for (int k = 0; k < 15; ++k) a += h2[k] * Wp3[k * 15 + j];
        h[j] = tanhf(a);
    }
    float ph[4];
    for (int j = 0; j < 4; ++j) {
        float a = bp4[j];
        for (int k = 0; k < 15; ++k) a += h[k] * Wp4[k * 4 + j];
        ph[j] = a;
    }
    return ph[0] + ph[1] * sinf(0.5f * th) + ph[2] * sth + ph[3] * sinf(1.5f * th);
}

// ROUND-7 STRUCTURE: the per-node compute is a ~48k-cycle SERIAL latency
// chain (1050 dependent ds_read->fma steps); makespan = (blocks/CU) x chain.
// R0's 403 fat 256-thr blocks = 1.57 chains/CU interleaved -> 31.6us; this
// round keeps the EXACT proven R0 per-thread math (float2 LDS reads, 1
// node/thread, VGPR ~100 measured) but in 64-thread one-wave blocks: 1611
// blocks = ~6.3 interleaved chains/CU -> LDS-issue floor ~11us.
// NO launch-bounds min-waves (round-5: forced cap -> 855 MB spill; round-6:
// released cap -> miscompile-class failure). Default allocator, proven body.
__global__ __launch_bounds__(64) void prep_kernel(
    const float* __restrict__ imv,
    const float* __restrict__ Ww1, const float* __restrict__ bw1,
    const float* __restrict__ Ww2, const float* __restrict__ bw2,
    const float* __restrict__ Ww3, const float* __restrict__ bw3,
    const float* __restrict__ Ww4, const float* __restrict__ bw4,
    const float* __restrict__ Wp1, const float* __restrict__ bp1,
    const float* __restrict__ Wp2, const float* __restrict__ bp2,
    const float* __restrict__ Wp3, const float* __restrict__ bp3,
    const float* __restrict__ Wp4, const float* __restrict__ bp4)
{
    const int t = threadIdx.x;

    if (blockIdx.x < WGB) {
        // ---- stage prescaled weights into LDS (broadcast-read thereafter) ----
        __shared__ __align__(16) float sW1[60], sb1[30], sW2[900], sb2[30],
                                       sW3[900], sb3[30], sW4[240], sb4[8];
        for (int i = t; i < 900; i += 64) {
            sW2[i] = CEXP * Ww2[i];
            sW3[i] = CEXP * Ww3[i];
        }
        for (int i = t; i < 240; i += 64) sW4[i] = Ww4[i];
        if (t < 60) sW1[t] = CEXP * Ww1[t];
        if (t < 30) {
            sb1[t] = CEXP * bw1[t];
            sb2[t] = CEXP * bw2[t];
            sb3[t] = CEXP * bw3[t];
        }
        if (t < 8) sb4[t] = bw4[t];
        __syncthreads();

        const int gid0 = blockIdx.x * 64 + t;
        const int gid  = gid0 < NNODES ? gid0 : NNODES - 1;   // clamp, no branch
        const int ix = gid % NN, iy = gid / NN;
        const float x0 = (float)ix * (1.0f / (float)NC);
        const float x1 = (float)iy * (1.0f / (float)NC);

        float h[30], a[30];
        #pragma unroll
        for (int j = 0; j < 30; ++j)
            h[j] = tanh_pre(fmaf(x1, sW1[30 + j], fmaf(x0, sW1[j], sb1[j])));

        // layer 2: 30 -> 30 (j-inner, float2 LDS reads) -- R0-proven body
        #pragma unroll
        for (int j = 0; j < 30; ++j) a[j] = sb2[j];
        #pragma unroll
        for (int k = 0; k < 30; ++k) {
            const float hk = h[k];
            #pragma unroll
            for (int jj = 0; jj < 15; ++jj) {
                const float2 w = *(const float2*)&sW2[k * 30 + 2 * jj];
                a[2 * jj]     = fmaf(hk, w.x, a[2 * jj]);
                a[2 * jj + 1] = fmaf(hk, w.y, a[2 * jj + 1]);
            }
        }
        #pragma unroll
        for (int j = 0; j < 30; ++j) a[j] = tanh_pre(a[j]);

        // layer 3: 30 -> 30
        #pragma unroll
        for (int j = 0; j < 30; ++j) h[j] = sb3[j];
        #pragma unroll
        for (int k = 0; k < 30; ++k) {
            const float ak = a[k];
            #pragma unroll
            for (int jj = 0; jj < 15; ++jj) {
                const float2 w = *(const float2*)&sW3[k * 30 + 2 * jj];
                h[2 * jj]     = fmaf(ak, w.x, h[2 * jj]);
                h[2 * jj + 1] = fmaf(ak, w.y, h[2 * jj + 1]);
            }
        }
        #pragma unroll
        for (int j = 0; j < 30; ++j) h[j] = tanh_pre(h[j]);

        // layer 4: 30 -> 8 (unscaled)
        float o[8];
        #pragma unroll
        for (int j = 0; j < 8; ++j) o[j] = sb4[j];
        #pragma unroll
        for (int k = 0; k < 30; ++k) {
            const float hk = h[k];
            #pragma unroll
            for (int jj = 0; jj < 4; ++jj) {
                const float2 w = *(const float2*)&sW4[k * 8 + 2 * jj];
                o[2 * jj]     = fmaf(hk, w.x, o[2 * jj]);
                o[2 * jj + 1] = fmaf(hk, w.y, o[2 * jj + 1]);
            }
        }

        // ---- fold yita(node): c_j = w_j + y * w_{4+j}  (16 B/node) ----
        const float ddx = x0 - imv[0], ddy = x1 - imv[1];
        const float rr  = sqrtf(fmaf(ddx, ddx, ddy * ddy));
        const float tt  = fminf(fmaxf(fmaf(2.5f, rr, -1.25f), 0.0f), 1.0f);
        const float tt3 = tt * tt * tt;
        const float yv  = fmaf(fmaf(fmaf(-6.0f, tt, 15.0f), tt, -10.0f), tt3, 1.0f);

        float4 v;
        v.x = fmaf(yv, o[4], o[0]);
        v.y = fmaf(yv, o[5], o[1]);
        v.z = fmaf(yv, o[6], o[2]);
        v.w = fmaf(yv, o[7], o[3]);
        if (gid0 < NNODES) g_ctab[gid] = v;   // only the store is predicated
        return;
    }

    // ---- s(theta) table blocks ----
    const int cell = (blockIdx.x - WGB) * 64 + t;
    if (cell < TABN) {
        const float hh = 4.0f / (float)TABN;
        const float p0 = -2.0f + hh * (float)cell;
        const float s0 = s_of_p(p0,      Wp1, bp1, Wp2, bp2, Wp3, bp3, Wp4, bp4);
        const float s1 = s_of_p(p0 + hh, Wp1, bp1, Wp2, bp2, Wp3, bp3, Wp4, bp4);
        float2 e; e.x = s0; e.y = s1 - s0;
        g_stab2[cell] = e;
    }
}

// 2 points per thread. Per point: one bilinear gather of the 4 folded coeffs
// (4x dwordx4), one 8 B s(theta) gather, ~70 VALU ops of closed-form geometry.
__global__ __launch_bounds__(256) void interior_kernel(
    const float4* __restrict__ x,      // two points per float4
    const float*  __restrict__ imv,
    const float*  __restrict__ lmbd,
    float* __restrict__ out, int n2)   // n2 = n/2
{
    const int idx = blockIdx.x * blockDim.x + threadIdx.x;
    if (idx >= n2) return;

    const float4 xx = x[idx];
    const float X0[2] = {xx.x, xx.z};
    const float X1[2] = {xx.y, xx.w};
    const float im0 = imv[0], im1 = imv[1], lam = lmbd[0];

    const float4* __restrict__ T = g_ctab;

    float res[2];
    #pragma unroll
    for (int p = 0; p < 2; ++p) {
        const float x0 = X0[p], x1 = X1[p];

        // ---- bilinear gather of folded coeffs c[0..4) from the 2-D grid ----
        const float fx = x0 * (float)NC;
        const float fy = x1 * (float)NC;
        int ix = (int)fx; ix = ix < 0 ? 0 : (ix > NC - 1 ? NC - 1 : ix);
        int iy = (int)fy; iy = iy < 0 ? 0 : (iy > NC - 1 ? NC - 1 : iy);
        const float frx = fx - (float)ix;
        const float fry = fy - (float)iy;

        const int k = iy * NN + ix;              // float4 units
        const float4 A = T[k],      B = T[k + 1];        // (ix,iy) (ix+1,iy)
        const float4 Cq = T[k + NN], D = T[k + NN + 1];  // row iy+1

        float cv[4];
        {
            const float r0x = fmaf(frx, B.x - A.x, A.x);
            const float r0y = fmaf(frx, B.y - A.y, A.y);
            const float r0z = fmaf(frx, B.z - A.z, A.z);
            const float r0w = fmaf(frx, B.w - A.w, A.w);
            const float r1x = fmaf(frx, D.x - Cq.x, Cq.x);
            const float r1y = fmaf(frx, D.y - Cq.y, Cq.y);
            const float r1z = fmaf(frx, D.z - Cq.z, Cq.z);
            const float r1w = fmaf(frx, D.w - Cq.w, Cq.w);
            cv[0] = fmaf(fry, r1x - r0x, r0x);
            cv[1] = fmaf(fry, r1y - r0y, r0y);
            cv[2] = fmaf(fry, r1z - r0z, r0z);
            cv[3] = fmaf(fry, r1w - r0w, r0w);
        }

        // ---- geometry about the interior vertex ----
        const float dx = x0 - im0, dy = x1 - im1;
        const float r  = sqrtf(fmaf(dx, dx, dy * dy));

        // yita(r) -- exact, still needed for the sp term
        const float t  = fminf(fmaxf(fmaf(2.5f, r, -1.25f), 0.0f), 1.0f);
        const float t3 = t * t * t;
        const float yv = fmaf(fmaf(fmaf(-6.0f, t, 15.0f), t, -10.0f), t3, 1.0f);

        // r^lambda (sqrt fast path for lambda == 0.5)
        float rl;
        if (lam == 0.5f) rl = sqrtf(r);
        else rl = __builtin_amdgcn_exp2f(lam * __builtin_amdgcn_logf(fmaxf(r, 1e-20f)));

        // diamond-angle parameter p(theta) in [-2,2], no trig
        const float l1n = fmaxf(fabsf(dx) + fabsf(dy), 1e-20f);
        const float u   = dy * __builtin_amdgcn_rcpf(l1n);
        const float pbk = (dy >= 0.0f) ? (2.0f - u) : (-2.0f - u);
        const float pth = (dx >= 0.0f) ? u : pbk;

        // s(theta) table gather: cell {s, ds}, one 8 B load
        const float fi = fminf(fmaxf(fmaf(pth, (float)(TABN / 4), (float)(TABN / 2)),
                                     0.0f), (float)TABN - 0.001f);
        const int   ii = (int)fi;
        const float fr = fi - (float)ii;
        const float2 sd = g_stab2[ii];
        const float sval = fmaf(fr, sd.y, sd.x);

        // singular functions at x (about origin), algebraically reduced:
        // vp0 = r0^0.5 sin(th/2) = copysign(sqrt((r0-x0)/2), x1)
        // vp1 = x1
        // vp2 = r0^1.5 sin(1.5 th) = x1*sqrt((r0+x0)/2) + x0*vp0
        const float r0 = sqrtf(fmaf(x0, x0, x1 * x1));
        const float Aq = sqrtf(fmaxf(0.0f, (r0 - x0) * 0.5f));
        const float Bq = sqrtf(fmaxf(0.0f, (r0 + x0) * 0.5f));
        const float vp0 = copysignf(Aq, x1);
        const float vp2 = fmaf(x1, Bq, x0 * vp0);

        // combine (yita already folded into cv[])
        float rp = cv[0];
        rp = fmaf(cv[1], vp0, rp);
        rp = fmaf(cv[2], x1, rp);
        rp = fmaf(cv[3], vp2, rp);
        res[p] = fmaf(sval * yv, rl, rp);
    }

    float2 o; o.x = res[0]; o.y = res[1];
    ((float2*)out)[idx] = o;
}

extern "C" void kernel_launch(void* const* d_in, const int* in_sizes, int n_in,
                              void* d_out, int out_size, void* d_ws, size_t ws_size,
                              hipStream_t stream) {
    const float4* x   = (const float4*)d_in[0];
    const float* imv  = (const float*)d_in[1];
    const float* lmbd = (const float*)d_in[2];
    const float* Ww1  = (const float*)d_in[3];
    const float* bw1  = (const float*)d_in[4];
    const float* Ww2  = (const float*)d_in[5];
    const float* bw2  = (const float*)d_in[6];
    const float* Ww3  = (const float*)d_in[7];
    const float* bw3  = (const float*)d_in[8];
    const float* Ww4  = (const float*)d_in[9];
    const float* bw4  = (const float*)d_in[10];
    const float* Wp1  = (const float*)d_in[11];
    const float* bp1  = (const float*)d_in[12];
    const float* Wp2  = (const float*)d_in[13];
    const float* bp2  = (const float*)d_in[14];
    const float* Wp3  = (const float*)d_in[15];
    const float* bp3  = (const float*)d_in[16];
    const float* Wp4  = (const float*)d_in[17];
    const float* bp4  = (const float*)d_in[18];
    float* out = (float*)d_out;

    const int n  = in_sizes[0] / 2;
    const int n2 = n / 2;

    // WGB one-wave blocks for the w-grid + SGB for the s-table.
    prep_kernel<<<WGB + SGB, 64, 0, stream>>>(
        imv,
        Ww1, bw1, Ww2, bw2, Ww3, bw3, Ww4, bw4,
        Wp1, bp1, Wp2, bp2, Wp3, bp3, Wp4, bp4);

    const int block = 256;
    const int grid = (n2 + block - 1) / block;
    interior_kernel<<<grid, block, 0, stream>>>(x, imv, lmbd, out, n2);
}

// Round 8
// 132.850 us; speedup vs baseline: 4.5533x; 1.0342x over previous
//
#include <hip/hip_runtime.h>
#include <math.h>

#define CEXP 2.8853900817779268f  // 2*log2(e): tanh(z) = 1 - 2/(2^(c*z)+1)
#define TABN 2048   // s(theta) table cells
#define NC   320    // w(x) grid cells per axis
#define NN   321    // w(x) grid nodes per axis
#define NNODES (NN * NN)                 // 103041
#define NCELLS (NC * NC)                 // 102400
#define WGB ((NNODES + 63) / 64)         // 1611 one-wave blocks for the w-grid
#define SGB (TABN / 64)                  // 32 one-wave blocks for the s-table

// Tables (rewritten every launch; kernel boundaries make them visible across
// XCDs). g_ctab[node] = {w0+y*w4, .., w3+y*w7} (yita folded, 16 B/node).
// g_qtab[cell] = 32 B quad record {c00: 4xf32 | d10: 4xbf16 | d01: 4xbf16}
// so interior reads ONE aligned 32 B line per point instead of 2 rows (~3
// lines). Cross-term dropped: |fx*fy*h^2*c''| ~ 1e-4; bf16 delta err ~3e-5 --
// both below the 2^-9 output-quantization floor (absmax bit-identical across
// NC=320/384 all session).
__device__ float4 g_ctab[NNODES];
__device__ float4 g_qtab[NCELLS * 2];   // 3.3 MB, L2-resident per XCD
__device__ float2 g_stab2[TABN];        // cell i: {s(p_i), s(p_{i+1}) - s(p_i)}

// tanh with the 2*log2(e) factor pre-folded into the incoming accumulator.
static __device__ __forceinline__ float tanh_pre(float z) {
    float e = __builtin_amdgcn_exp2f(z);
    float r = __builtin_amdgcn_rcpf(e + 1.0f);
    return fmaf(-2.0f, r, 1.0f);
}

// pack two floats to bf16 (round-to-nearest-even) in one uint {lo=a, hi=b}
static __device__ __forceinline__ unsigned bf16x2(float a, float b) {
    unsigned ua = __float_as_uint(a);
    ua = (ua + 0x7FFFu + ((ua >> 16) & 1u)) >> 16;
    unsigned ub = __float_as_uint(b);
    ub = (ub + 0x7FFFu + ((ub >> 16) & 1u)) & 0xFFFF0000u;
    return ua | ub;
}

// Full phi-branch value s(theta(p)) at diamond-angle parameter p in [-2,2].
// ROUND-2 LESSON: keep this UN-unrolled with libm tanhf (the unrolled
// tanh_pre version spilled to scratch and became a long serial tail).
static __device__ float s_of_p(float pth,
    const float* __restrict__ Wp1, const float* __restrict__ bp1,
    const float* __restrict__ Wp2, const float* __restrict__ bp2,
    const float* __restrict__ Wp3, const float* __restrict__ bp3,
    const float* __restrict__ Wp4, const float* __restrict__ bp4)
{
    float th;
    if (pth >= -1.0f && pth <= 1.0f) {
        th = atanf(pth / (1.0f - fabsf(pth)));      // /0 -> inf -> atan=pi/2 ok
    } else if (pth > 1.0f) {
        const float uu = 2.0f - pth;                // [0,1)
        th = (float)M_PI - atanf(uu / (1.0f - uu));
    } else {
        const float uu = -2.0f - pth;               // (-1,0]
        th = -(float)M_PI + atanf(-uu / (1.0f + uu));
    }
    const float cth = cosf(th), sth = sinf(th);

    // phi-MLP in f32 with exact tanh: 2 -> 15 -> 15 -> 15 -> 4
    float h[15], h2[15];
    for (int j = 0; j < 15; ++j)
        h[j] = tanhf(cth * Wp1[j] + sth * Wp1[15 + j] + bp1[j]);
    for (int j = 0; j < 15; ++j) {
        float a = bp2[j];
        for (int k = 0; k < 15; ++k) a += h[k] * Wp2[k * 15 + j];
        h2[j] = tanhf(a);
    }
    for (int j = 0; j < 15; ++j) {
        float a = bp3[j];
        for (int k = 0; k < 15; ++k) a += h2[k] * Wp3[k * 15 + j];
        h[j] = tanhf(a);
    }
    float ph[4];
    for (int j = 0; j < 4; ++j) {
        float a = bp4[j];
        for (int k = 0; k < 15; ++k) a += h[k] * Wp4[k * 4 + j];
        ph[j] = a;
    }
    return ph[0] + ph[1] * sinf(0.5f * th) + ph[2] * sth + ph[3] * sinf(1.5f * th);
}

// w-grid prep: BYTE-IDENTICAL body to round 7's passing kernel (latency-bound
// ~31us; known-good codegen -- do not touch).
__global__ __launch_bounds__(64) void prep_kernel(
    const float* __restrict__ imv,
    const float* __restrict__ Ww1, const float* __restrict__ bw1,
    const float* __restrict__ Ww2, const float* __restrict__ bw2,
    const float* __restrict__ Ww3, const float* __restrict__ bw3,
    const float* __restrict__ Ww4, const float* __restrict__ bw4,
    const float* __restrict__ Wp1, const float* __restrict__ bp1,
    const float* __restrict__ Wp2, const float* __restrict__ bp2,
    const float* __restrict__ Wp3, const float* __restrict__ bp3,
    const float* __restrict__ Wp4, const float* __restrict__ bp4)
{
    const int t = threadIdx.x;

    if (blockIdx.x < WGB) {
        // ---- stage prescaled weights into LDS (broadcast-read thereafter) ----
        __shared__ __align__(16) float sW1[60], sb1[30], sW2[900], sb2[30],
                                       sW3[900], sb3[30], sW4[240], sb4[8];
        for (int i = t; i < 900; i += 64) {
            sW2[i] = CEXP * Ww2[i];
            sW3[i] = CEXP * Ww3[i];
        }
        for (int i = t; i < 240; i += 64) sW4[i] = Ww4[i];
        if (t < 60) sW1[t] = CEXP * Ww1[t];
        if (t < 30) {
            sb1[t] = CEXP * bw1[t];
            sb2[t] = CEXP * bw2[t];
            sb3[t] = CEXP * bw3[t];
        }
        if (t < 8) sb4[t] = bw4[t];
        __syncthreads();

        const int gid0 = blockIdx.x * 64 + t;
        const int gid  = gid0 < NNODES ? gid0 : NNODES - 1;   // clamp, no branch
        const int ix = gid % NN, iy = gid / NN;
        const float x0 = (float)ix * (1.0f / (float)NC);
        const float x1 = (float)iy * (1.0f / (float)NC);

        float h[30], a[30];
        #pragma unroll
        for (int j = 0; j < 30; ++j)
            h[j] = tanh_pre(fmaf(x1, sW1[30 + j], fmaf(x0, sW1[j], sb1[j])));

        // layer 2: 30 -> 30 (j-inner, float2 LDS reads)
        #pragma unroll
        for (int j = 0; j < 30; ++j) a[j] = sb2[j];
        #pragma unroll
        for (int k = 0; k < 30; ++k) {
            const float hk = h[k];
            #pragma unroll
            for (int jj = 0; jj < 15; ++jj) {
                const float2 w = *(const float2*)&sW2[k * 30 + 2 * jj];
                a[2 * jj]     = fmaf(hk, w.x, a[2 * jj]);
                a[2 * jj + 1] = fmaf(hk, w.y, a[2 * jj + 1]);
            }
        }
        #pragma unroll
        for (int j = 0; j < 30; ++j) a[j] = tanh_pre(a[j]);

        // layer 3: 30 -> 30
        #pragma unroll
        for (int j = 0; j < 30; ++j) h[j] = sb3[j];
        #pragma unroll
        for (int k = 0; k < 30; ++k) {
            const float ak = a[k];
            #pragma unroll
            for (int jj = 0; jj < 15; ++jj) {
                const float2 w = *(const float2*)&sW3[k * 30 + 2 * jj];
                h[2 * jj]     = fmaf(ak, w.x, h[2 * jj]);
                h[2 * jj + 1] = fmaf(ak, w.y, h[2 * jj + 1]);
            }
        }
        #pragma unroll
        for (int j = 0; j < 30; ++j) h[j] = tanh_pre(h[j]);

        // layer 4: 30 -> 8 (unscaled)
        float o[8];
        #pragma unroll
        for (int j = 0; j < 8; ++j) o[j] = sb4[j];
        #pragma unroll
        for (int k = 0; k < 30; ++k) {
            const float hk = h[k];
            #pragma unroll
            for (int jj = 0; jj < 4; ++jj) {
                const float2 w = *(const float2*)&sW4[k * 8 + 2 * jj];
                o[2 * jj]     = fmaf(hk, w.x, o[2 * jj]);
                o[2 * jj + 1] = fmaf(hk, w.y, o[2 * jj + 1]);
            }
        }

        // ---- fold yita(node): c_j = w_j + y * w_{4+j}  (16 B/node) ----
        const float ddx = x0 - imv[0], ddy = x1 - imv[1];
        const float rr  = sqrtf(fmaf(ddx, ddx, ddy * ddy));
        const float tt  = fminf(fmaxf(fmaf(2.5f, rr, -1.25f), 0.0f), 1.0f);
        const float tt3 = tt * tt * tt;
        const float yv  = fmaf(fmaf(fmaf(-6.0f, tt, 15.0f), tt, -10.0f), tt3, 1.0f);

        float4 v;
        v.x = fmaf(yv, o[4], o[0]);
        v.y = fmaf(yv, o[5], o[1]);
        v.z = fmaf(yv, o[6], o[2]);
        v.w = fmaf(yv, o[7], o[3]);
        if (gid0 < NNODES) g_ctab[gid] = v;   // only the store is predicated
        return;
    }

    // ---- s(theta) table blocks ----
    const int cell = (blockIdx.x - WGB) * 64 + t;
    if (cell < TABN) {
        const float hh = 4.0f / (float)TABN;
        const float p0 = -2.0f + hh * (float)cell;
        const float s0 = s_of_p(p0,      Wp1, bp1, Wp2, bp2, Wp3, bp3, Wp4, bp4);
        const float s1 = s_of_p(p0 + hh, Wp1, bp1, Wp2, bp2, Wp3, bp3, Wp4, bp4);
        float2 e; e.x = s0; e.y = s1 - s0;
        g_stab2[cell] = e;
    }
}

// Cell-quad packing: node table -> 32 B/cell {c00 f32x4, d10 bf16x4, d01
// bf16x4}. 400 blocks of coalesced reads/writes, ~2us. Separate launch =
// visibility of g_ctab across XCDs.
__global__ __launch_bounds__(256) void pack_kernel() {
    const int c = blockIdx.x * 256 + threadIdx.x;
    if (c >= NCELLS) return;
    const int ix = c % NC, iy = c / NC;
    const int n = iy * NN + ix;
    const float4 c00 = g_ctab[n];
    const float4 c10 = g_ctab[n + 1];
    const float4 c01 = g_ctab[n + NN];
    float4 d;
    d.x = __uint_as_float(bf16x2(c10.x - c00.x, c10.y - c00.y));
    d.y = __uint_as_float(bf16x2(c10.z - c00.z, c10.w - c00.w));
    d.z = __uint_as_float(bf16x2(c01.x - c00.x, c01.y - c00.y));
    d.w = __uint_as_float(bf16x2(c01.z - c00.z, c01.w - c00.w));
    g_qtab[2 * c]     = c00;
    g_qtab[2 * c + 1] = d;
}

// 2 points per thread. Per point: ONE aligned 32 B quad load (was 2 rows /
// ~3 lines), one 8 B s(theta) gather (16 KB table, L1-resident), ~60 VALU.
__global__ __launch_bounds__(256) void interior_kernel(
    const float4* __restrict__ x,      // two points per float4
    const float*  __restrict__ imv,
    const float*  __restrict__ lmbd,
    float* __restrict__ out, int n2)   // n2 = n/2
{
    const int idx = blockIdx.x * blockDim.x + threadIdx.x;
    if (idx >= n2) return;

    const float4 xx = x[idx];
    const float X0[2] = {xx.x, xx.z};
    const float X1[2] = {xx.y, xx.w};
    const float im0 = imv[0], im1 = imv[1], lam = lmbd[0];

    const float4* __restrict__ Q = g_qtab;

    float res[2];
    #pragma unroll
    for (int p = 0; p < 2; ++p) {
        const float x0 = X0[p], x1 = X1[p];

        // ---- one-line gather of the folded cell quad ----
        const float fx = x0 * (float)NC;
        const float fy = x1 * (float)NC;
        int ix = (int)fx; ix = ix < 0 ? 0 : (ix > NC - 1 ? NC - 1 : ix);
        int iy = (int)fy; iy = iy < 0 ? 0 : (iy > NC - 1 ? NC - 1 : iy);
        const float frx = fx - (float)ix;
        const float fry = fy - (float)iy;

        const int cell = iy * NC + ix;
        const float4 c00 = Q[2 * cell];
        const float4 dd  = Q[2 * cell + 1];
        const unsigned ux = __float_as_uint(dd.x), uy = __float_as_uint(dd.y);
        const unsigned uz = __float_as_uint(dd.z), uw = __float_as_uint(dd.w);

        float cv[4];
        cv[0] = fmaf(frx, __uint_as_float(ux << 16),
                fmaf(fry, __uint_as_float(uz << 16),          c00.x));
        cv[1] = fmaf(frx, __uint_as_float(ux & 0xFFFF0000u),
                fmaf(fry, __uint_as_float(uz & 0xFFFF0000u),  c00.y));
        cv[2] = fmaf(frx, __uint_as_float(uy << 16),
                fmaf(fry, __uint_as_float(uw << 16),          c00.z));
        cv[3] = fmaf(frx, __uint_as_float(uy & 0xFFFF0000u),
                fmaf(fry, __uint_as_float(uw & 0xFFFF0000u),  c00.w));

        // ---- geometry about the interior vertex ----
        const float dx = x0 - im0, dy = x1 - im1;
        const float r  = sqrtf(fmaf(dx, dx, dy * dy));

        // yita(r) -- exact, still needed for the sp term
        const float t  = fminf(fmaxf(fmaf(2.5f, r, -1.25f), 0.0f), 1.0f);
        const float t3 = t * t * t;
        const float yv = fmaf(fmaf(fmaf(-6.0f, t, 15.0f), t, -10.0f), t3, 1.0f);

        // r^lambda (sqrt fast path for lambda == 0.5)
        float rl;
        if (lam == 0.5f) rl = sqrtf(r);
        else rl = __builtin_amdgcn_exp2f(lam * __builtin_amdgcn_logf(fmaxf(r, 1e-20f)));

        // diamond-angle parameter p(theta) in [-2,2], no trig
        const float l1n = fmaxf(fabsf(dx) + fabsf(dy), 1e-20f);
        const float u   = dy * __builtin_amdgcn_rcpf(l1n);
        const float pbk = (dy >= 0.0f) ? (2.0f - u) : (-2.0f - u);
        const float pth = (dx >= 0.0f) ? u : pbk;

        // s(theta) table gather: cell {s, ds}, one 8 B load
        const float fi = fminf(fmaxf(fmaf(pth, (float)(TABN / 4), (float)(TABN / 2)),
                                     0.0f), (float)TABN - 0.001f);
        const int   ii = (int)fi;
        const float fr = fi - (float)ii;
        const float2 sd = g_stab2[ii];
        const float sval = fmaf(fr, sd.y, sd.x);

        // singular functions at x (about origin), algebraically reduced:
        // vp0 = r0^0.5 sin(th/2) = copysign(sqrt((r0-x0)/2), x1)
        // vp1 = x1
        // vp2 = r0^1.5 sin(1.5 th) = x1*sqrt((r0+x0)/2) + x0*vp0
        const float r0 = sqrtf(fmaf(x0, x0, x1 * x1));
        const float Aq = sqrtf(fmaxf(0.0f, (r0 - x0) * 0.5f));
        const float Bq = sqrtf(fmaxf(0.0f, (r0 + x0) * 0.5f));
        const float vp0 = copysignf(Aq, x1);
        const float vp2 = fmaf(x1, Bq, x0 * vp0);

        // combine (yita already folded into cv[])
        float rp = cv[0];
        rp = fmaf(cv[1], vp0, rp);
        rp = fmaf(cv[2], x1, rp);
        rp = fmaf(cv[3], vp2, rp);
        res[p] = fmaf(sval * yv, rl, rp);
    }

    float2 o; o.x = res[0]; o.y = res[1];
    ((float2*)out)[idx] = o;
}

extern "C" void kernel_launch(void* const* d_in, const int* in_sizes, int n_in,
                              void* d_out, int out_size, void* d_ws, size_t ws_size,
                              hipStream_t stream) {
    const float4* x   = (const float4*)d_in[0];
    const float* imv  = (const float*)d_in[1];
    const float* lmbd = (const float*)d_in[2];
    const float* Ww1  = (const float*)d_in[3];
    const float* bw1  = (const float*)d_in[4];
    const float* Ww2  = (const float*)d_in[5];
    const float* bw2  = (const float*)d_in[6];
    const float* Ww3  = (const float*)d_in[7];
    const float* bw3  = (const float*)d_in[8];
    const float* Ww4  = (const float*)d_in[9];
    const float* bw4  = (const float*)d_in[10];
    const float* Wp1  = (const float*)d_in[11];
    const float* bp1  = (const float*)d_in[12];
    const float* Wp2  = (const float*)d_in[13];
    const float* bp2  = (const float*)d_in[14];
    const float* Wp3  = (const float*)d_in[15];
    const float* bp3  = (const float*)d_in[16];
    const float* Wp4  = (const float*)d_in[17];
    const float* bp4  = (const float*)d_in[18];
    float* out = (float*)d_out;

    const int n  = in_sizes[0] / 2;
    const int n2 = n / 2;

    // prep (w-grid + s-table) -> pack (cell quads) -> interior.
    prep_kernel<<<WGB + SGB, 64, 0, stream>>>(
        imv,
        Ww1, bw1, Ww2, bw2, Ww3, bw3, Ww4, bw4,
        Wp1, bp1, Wp2, bp2, Wp3, bp3, Wp4, bp4);

    pack_kernel<<<(NCELLS + 255) / 256, 256, 0, stream>>>();

    const int block = 256;
    const int grid = (n2 + block - 1) / block;
    interior_kernel<<<grid, block, 0, stream>>>(x, imv, lmbd, out, n2);
}